// Round 1
// baseline (508.987 us; speedup 1.0000x reference)
//
#include <hip/hip_runtime.h>

// Problem: x[B,C,H,W] fp32, percents[B] fp32.
// lengths[b] = (int)(W * percents[b]); out[b,c,h,w] = (w >= lengths[b]) ? 0 : x[...]
// B=16, C=64, H=80, W=1024.
//
// The mask pattern along W depends only on b, so a thread's classification
// (fully-live / fully-dead / straddle) is identical for every row of a batch.
// Each block owns 20 contiguous rows of one batch: classify once, then stream.

typedef float vf4 __attribute__((ext_vector_type(4)));

constexpr int kB = 16;
constexpr int kC = 64;
constexpr int kH = 80;
constexpr int kW = 1024;
constexpr int kRows = kC * kH;                   // 5120 rows per batch
constexpr int kVecPerRow = kW / 4;               // 256 float4 per row == blockDim.x
constexpr int kBlocksX = 256;                    // blocks along the row dimension
constexpr int kRowsPerBlock = kRows / kBlocksX;  // 20 rows per block

__global__ __launch_bounds__(256) void mask_cnn_kernel(
    const vf4* __restrict__ x, const float* __restrict__ percents,
    vf4* __restrict__ out) {
    const int b = blockIdx.y;
    const int tid = threadIdx.x;
    const int w4 = tid * 4;  // first W position of this thread's float4

    // Match jnp: (W * percents).astype(int32) -> fp32 multiply, truncate.
    const int len = (int)((float)kW * percents[b]);  // wave-uniform scalar load

    // Flat float4 index of this thread's element in the first owned row.
    int idx = (b * kRows + blockIdx.x * kRowsPerBlock) * kVecPerRow + tid;

    if (w4 + 4 <= len) {
        // Fully live: pure streaming copy, 4 rows of loads in flight.
#pragma unroll
        for (int r = 0; r < kRowsPerBlock; r += 4) {
            vf4 v0 = __builtin_nontemporal_load(&x[idx + 0 * kVecPerRow]);
            vf4 v1 = __builtin_nontemporal_load(&x[idx + 1 * kVecPerRow]);
            vf4 v2 = __builtin_nontemporal_load(&x[idx + 2 * kVecPerRow]);
            vf4 v3 = __builtin_nontemporal_load(&x[idx + 3 * kVecPerRow]);
            __builtin_nontemporal_store(v0, &out[idx + 0 * kVecPerRow]);
            __builtin_nontemporal_store(v1, &out[idx + 1 * kVecPerRow]);
            __builtin_nontemporal_store(v2, &out[idx + 2 * kVecPerRow]);
            __builtin_nontemporal_store(v3, &out[idx + 3 * kVecPerRow]);
            idx += 4 * kVecPerRow;
        }
    } else if (w4 >= len) {
        // Fully masked: never read, stream zeros.
        const vf4 z = {0.f, 0.f, 0.f, 0.f};
#pragma unroll
        for (int r = 0; r < kRowsPerBlock; r += 4) {
            __builtin_nontemporal_store(z, &out[idx + 0 * kVecPerRow]);
            __builtin_nontemporal_store(z, &out[idx + 1 * kVecPerRow]);
            __builtin_nontemporal_store(z, &out[idx + 2 * kVecPerRow]);
            __builtin_nontemporal_store(z, &out[idx + 3 * kVecPerRow]);
            idx += 4 * kVecPerRow;
        }
    } else {
        // Straddles the boundary (at most one thread column per batch).
        const bool k0 = (w4 + 0) < len;
        const bool k1 = (w4 + 1) < len;
        const bool k2 = (w4 + 2) < len;
        const bool k3 = (w4 + 3) < len;
#pragma unroll
        for (int r = 0; r < kRowsPerBlock; ++r) {
            vf4 v = __builtin_nontemporal_load(&x[idx]);
            v.x = k0 ? v.x : 0.f;
            v.y = k1 ? v.y : 0.f;
            v.z = k2 ? v.z : 0.f;
            v.w = k3 ? v.w : 0.f;
            __builtin_nontemporal_store(v, &out[idx]);
            idx += kVecPerRow;
        }
    }
}

extern "C" void kernel_launch(void* const* d_in, const int* in_sizes, int n_in,
                              void* d_out, int out_size, void* d_ws, size_t ws_size,
                              hipStream_t stream) {
    const vf4* x = (const vf4*)d_in[0];
    const float* percents = (const float*)d_in[1];
    vf4* out = (vf4*)d_out;

    dim3 grid(kBlocksX, kB);  // 256 x 16 = 4096 blocks, 20 rows each
    dim3 block(256);          // one thread per float4 within a row
    mask_cnn_kernel<<<grid, block, 0, stream>>>(x, percents, out);
}